// Round 5
// baseline (2701.219 us; speedup 1.0000x reference)
//
#include <hip/hip_runtime.h>

// zhannRNN: x[8,512,512] -> xp GEMM -> 512-step tanh recurrence (HID=2048) -> out GEMM [*,128]
//   Phase 1: xp[t][b][j] = x @ W_ih^T + b_ih + b_hh   (bf16 MFMA GEMM; also zeroes flags)
//   Phase 2: 64 persistent wgs, W_hh in VGPRs. Flag-gated IC-scope exchange:
//            producers store h (sc0 sc1 -> Infinity Cache), drain, raise flags[g]=t+1;
//            consumer waves poll 64B of flags, then bulk-load their h chunk ONCE.
//            No XCD placement assumptions -> cannot hang (all traffic at coherence point).
//   Phase 3: out = hs @ W_out^T + b_out               (bf16 MFMA GEMM)

#define IN_K   512
#define HID    2048
#define OUTN   128
#define BB     8
#define TSTEPS 512
#define NWG    64

typedef __bf16 bf16x8 __attribute__((ext_vector_type(8)));
typedef unsigned short u16x8 __attribute__((ext_vector_type(8)));
typedef unsigned int u32x4 __attribute__((ext_vector_type(4)));
typedef int i32x4 __attribute__((ext_vector_type(4)));
typedef float f32v4 __attribute__((ext_vector_type(4)));

union Frag8 { u16x8 u; bf16x8 b; u32x4 d; };

__device__ __forceinline__ unsigned short f2bf(float f) {
  unsigned int u = __float_as_uint(f);
  return (unsigned short)((u + 0x7FFFu + ((u >> 16) & 1u)) >> 16);  // RNE
}

__device__ __forceinline__ float tanh_fast(float x) {
  return 1.0f - 2.0f / (__expf(2.0f * x) + 1.0f);  // ~1e-6 abs err, << bf16 rounding
}

// ---------------- GEMM (phases 1 & 3) ----------------
template<int EPI>
__global__ __launch_bounds__(256, 2)
void gemm_kernel(const void* __restrict__ Aptr, const float* __restrict__ Bptr,
                 const float* __restrict__ bias0, const float* __restrict__ bias1,
                 float* __restrict__ Cout, const int Kdim, const int Ndim,
                 int* __restrict__ bar)
{
  if (EPI == 0 && blockIdx.x == 0 && blockIdx.y == 0 && threadIdx.x < 72)
    bar[threadIdx.x] = 0;   // flags[64] live at bar[8..72)
  __shared__ __align__(16) unsigned short As[64][56];
  __shared__ __align__(16) unsigned short Bs[64][56];

  const int m0 = blockIdx.x * 64;
  const int n0 = blockIdx.y * 64;
  const int tid = threadIdx.x;
  const int w = tid >> 6, l = tid & 63;
  const int l15 = l & 15, lk = (l >> 4) * 8;
  const int wm = (w >> 1) * 32, wn = (w & 1) * 32;

  f32v4 acc[2][2];
  #pragma unroll
  for (int mt = 0; mt < 2; ++mt)
    #pragma unroll
    for (int nt = 0; nt < 2; ++nt)
      #pragma unroll
      for (int r = 0; r < 4; ++r) acc[mt][nt][r] = 0.0f;

  for (int k0 = 0; k0 < Kdim; k0 += 32) {
    __syncthreads();
    if (EPI == 0) {
      const float* A = (const float*)Aptr;
      const int r = tid >> 3, c4 = (tid & 7) * 4;
      #pragma unroll
      for (int it = 0; it < 2; ++it) {
        const float4 v = *(const float4*)(A + (size_t)(m0 + r + it * 32) * Kdim + k0 + c4);
        unsigned short* d = &As[r + it * 32][c4];
        d[0] = f2bf(v.x); d[1] = f2bf(v.y); d[2] = f2bf(v.z); d[3] = f2bf(v.w);
      }
    } else {
      const unsigned short* A = (const unsigned short*)Aptr;
      const int r = tid >> 2, c8 = (tid & 3) * 8;
      const u16x8 v = *(const u16x8*)(A + (size_t)(m0 + r) * Kdim + k0 + c8);
      *(u16x8*)&As[r][c8] = v;
    }
    {
      const int r = tid >> 3, c4 = (tid & 7) * 4;
      #pragma unroll
      for (int it = 0; it < 2; ++it) {
        const float4 v = *(const float4*)(Bptr + (size_t)(n0 + r + it * 32) * Kdim + k0 + c4);
        unsigned short* d = &Bs[r + it * 32][c4];
        d[0] = f2bf(v.x); d[1] = f2bf(v.y); d[2] = f2bf(v.z); d[3] = f2bf(v.w);
      }
    }
    __syncthreads();

    Frag8 af[2], bg[2];
    #pragma unroll
    for (int mt = 0; mt < 2; ++mt) af[mt].u = *(const u16x8*)&As[wm + mt * 16 + l15][lk];
    #pragma unroll
    for (int nt = 0; nt < 2; ++nt) bg[nt].u = *(const u16x8*)&Bs[wn + nt * 16 + l15][lk];
    #pragma unroll
    for (int mt = 0; mt < 2; ++mt)
      #pragma unroll
      for (int nt = 0; nt < 2; ++nt)
        acc[mt][nt] = __builtin_amdgcn_mfma_f32_16x16x32_bf16(af[mt].b, bg[nt].b, acc[mt][nt], 0, 0, 0);
  }

  #pragma unroll
  for (int mt = 0; mt < 2; ++mt)
    #pragma unroll
    for (int nt = 0; nt < 2; ++nt)
      #pragma unroll
      for (int r = 0; r < 4; ++r) {
        const int m = m0 + wm + mt * 16 + (l >> 4) * 4 + r;
        const int n = n0 + wn + nt * 16 + l15;
        float v = acc[mt][nt][r];
        if (EPI == 0) {
          v += bias0[n] + bias1[n];
          const int b = m >> 9, t = m & 511;
          Cout[((size_t)t * BB + b) * Ndim + n] = v;
        } else {
          v += bias0[n];
          Cout[(size_t)m * Ndim + n] = v;
        }
      }
}

// ---------------- Phase 2: flag-gated IC-scope scan ----------------
__global__ __launch_bounds__(256, 1)
void scan_kernel(const float* __restrict__ Whh, const float* __restrict__ xp,
                 unsigned short* __restrict__ hs, int* __restrict__ bar)
{
  const int g = blockIdx.x;
  const int tid = threadIdx.x;
  const int w = tid >> 6, l = tid & 63;     // wave w owns K-chunk [w*512, w*512+512)
  const int l15 = l & 15, lk = (l >> 4) * 8;
  const int jbase = g * 32;                 // wg owns output neurons [jbase, jbase+32)

  // Preload W_hh slice as MFMA B-fragments (128 VGPRs), bf16.
  Frag8 Bw[2][16];
  #pragma unroll
  for (int nt = 0; nt < 2; ++nt) {
    const int j = jbase + nt * 16 + l15;
    #pragma unroll
    for (int kc = 0; kc < 16; ++kc) {
      const int k = w * 512 + kc * 32 + lk;
      const float4* p = (const float4*)(Whh + (size_t)j * HID + k);
      const float4 u0 = p[0], u1 = p[1];
      Frag8 f;
      f.u[0] = f2bf(u0.x); f.u[1] = f2bf(u0.y); f.u[2] = f2bf(u0.z); f.u[3] = f2bf(u0.w);
      f.u[4] = f2bf(u1.x); f.u[5] = f2bf(u1.y); f.u[6] = f2bf(u1.z); f.u[7] = f2bf(u1.w);
      Bw[nt][kc] = f;
    }
  }

  __shared__ float red[4][2][16][16];  // per-wave partial C tiles, 8KB
  int* flags = bar + 8;
  const int om = tid >> 4;             // (tid<128) batch index
  const int oj2 = (tid & 15) * 2;      // thread handles j-offsets oj2, oj2+1
  const int half = oj2 >> 4, col = oj2 & 15;
  const int arow = l15 & 7;            // A rows 8..15 duplicate 0..7 (same addr -> coalesced)
  const int* fp = flags + w * 16;      // wave w's producers: wgs w*16 .. w*16+15

  for (int t = 0; t < TSTEPS; ++t) {
    // xp load (independent of h) — compiler-managed wait; overlaps the poll
    float xv0 = 0.f, xv1 = 0.f;
    if (tid < 128) {
      const float2 xv = *(const float2*)(xp + ((size_t)t * BB + om) * HID + jbase + oj2);
      xv0 = xv.x; xv1 = xv.y;
    }

    f32v4 acc0, acc1;
    #pragma unroll
    for (int r = 0; r < 4; ++r) { acc0[r] = 0.f; acc1[r] = 0.f; }

    if (t > 0) {  // h_{-1} == 0
      // 1) cheap flag poll (64B per iteration, IC scope)
      i32x4 f0, f1, f2, f3;
      while (true) {
        asm volatile("global_load_dwordx4 %0, %4, off sc0 sc1\n\t"
                     "global_load_dwordx4 %1, %4, off offset:16 sc0 sc1\n\t"
                     "global_load_dwordx4 %2, %4, off offset:32 sc0 sc1\n\t"
                     "global_load_dwordx4 %3, %4, off offset:48 sc0 sc1"
                     : "=v"(f0), "=v"(f1), "=v"(f2), "=v"(f3) : "v"(fp));
        asm volatile("s_waitcnt vmcnt(0)" ::: "memory");
        __builtin_amdgcn_sched_barrier(0);
        int mn = min(min(min(f0[0], f0[1]), min(f0[2], f0[3])),
                     min(min(f1[0], f1[1]), min(f1[2], f1[3])));
        mn = min(mn, min(min(min(f2[0], f2[1]), min(f2[2], f2[3])),
                         min(min(f3[0], f3[1]), min(f3[2], f3[3]))));
        if (mn >= t) break;
      }
      // 2) bulk-load h_{t-1} chunk exactly once
      const unsigned short* hb = hs + ((size_t)arow * TSTEPS + (t - 1)) * HID + w * 512 + lk;
      Frag8 a[16];
      #pragma unroll
      for (int kc = 0; kc < 16; ++kc) {
        asm volatile("global_load_dwordx4 %0, %1, off offset:%2 sc0 sc1"
                     : "=v"(a[kc].d) : "v"(hb), "n"(kc * 64));
      }
      asm volatile("s_waitcnt vmcnt(0)" ::: "memory");
      __builtin_amdgcn_sched_barrier(0);  // rule #18: MFMAs stay after the waitcnt
      #pragma unroll
      for (int kc = 0; kc < 16; ++kc) {
        acc0 = __builtin_amdgcn_mfma_f32_16x16x32_bf16(a[kc].b, Bw[0][kc].b, acc0, 0, 0, 0);
        acc1 = __builtin_amdgcn_mfma_f32_16x16x32_bf16(a[kc].b, Bw[1][kc].b, acc1, 0, 0, 0);
      }
    }

    // cross-wave K-reduction via LDS
    #pragma unroll
    for (int r = 0; r < 4; ++r) {
      red[w][0][(l >> 4) * 4 + r][l15] = acc0[r];
      red[w][1][(l >> 4) * 4 + r][l15] = acc1[r];
    }
    __syncthreads();

    if (tid < 128) {
      float s0 = red[0][half][om][col]     + red[1][half][om][col]
               + red[2][half][om][col]     + red[3][half][om][col]     + xv0;
      float s1 = red[0][half][om][col + 1] + red[1][half][om][col + 1]
               + red[2][half][om][col + 1] + red[3][half][om][col + 1] + xv1;
      const float h0 = tanh_fast(s0), h1 = tanh_fast(s1);
      const unsigned int packed = (unsigned int)f2bf(h0) | ((unsigned int)f2bf(h1) << 16);
      unsigned int* hp = (unsigned int*)(hs + ((size_t)om * TSTEPS + t) * HID + jbase + oj2);
      asm volatile("global_store_dword %0, %1, off sc0 sc1" :: "v"(hp), "v"(packed) : "memory");
    }
    // order: h stores performed at IC -> wg-wide -> raise flag
    asm volatile("s_waitcnt vmcnt(0)" ::: "memory");
    __syncthreads();
    if (tid == 0) {
      const int fl = t + 1;
      asm volatile("global_store_dword %0, %1, off sc0 sc1"
                   :: "v"(&flags[g]), "v"(fl) : "memory");
    }
  }
}

extern "C" void kernel_launch(void* const* d_in, const int* in_sizes, int n_in,
                              void* d_out, int out_size, void* d_ws, size_t ws_size,
                              hipStream_t stream)
{
  (void)in_sizes; (void)n_in; (void)out_size; (void)ws_size;
  const float* x    = (const float*)d_in[0];
  const float* Wih  = (const float*)d_in[1];
  const float* bih  = (const float*)d_in[2];
  const float* Whh  = (const float*)d_in[3];
  const float* bhh  = (const float*)d_in[4];
  const float* Wout = (const float*)d_in[5];
  const float* bout = (const float*)d_in[6];
  float* out = (float*)d_out;

  char* ws = (char*)d_ws;
  float* xp          = (float*)(ws);                                // [512][8][2048] fp32, 32 MiB
  unsigned short* hs = (unsigned short*)(ws + (size_t)(32 << 20));  // [8][512][2048] bf16, 16 MiB
  int* bar           = (int*)(ws + (size_t)(48 << 20));             // flags[64] at bar+8

  // Phase 1: xp = x @ W_ih^T + b_ih + b_hh (zeroes flags)
  gemm_kernel<0><<<dim3(64, 32), 256, 0, stream>>>(x, Wih, bih, bhh, xp, IN_K, HID, bar);
  // Phase 2: flag-gated sequential scan
  scan_kernel<<<dim3(NWG), 256, 0, stream>>>(Whh, xp, hs, bar);
  // Phase 3: out = hs @ W_out^T + b_out
  gemm_kernel<1><<<dim3(64, 2), 256, 0, stream>>>(hs, Wout, bout, nullptr, out, HID, OUTN, bar);
}

// Round 6
// 2376.530 us; speedup vs baseline: 1.1366x; 1.1366x over previous
//
#include <hip/hip_runtime.h>

// zhannRNN: x[8,512,512] -> xp GEMM -> 512-step tanh recurrence (HID=2048) -> out GEMM [*,128]
//   Phase 0: sentinel-fill hs with 0xFF80FF80 via WRITE-THROUGH stores (no dirty L2 lines)
//   Phase 1: xp[t][b][j] = x @ W_ih^T + b_ih + b_hh      (bf16 MFMA GEMM)
//   Phase 2: persistent scan, 64 wgs, W_hh in VGPRs. Exchange protocol:
//            producers write h via non-returning global_atomic_swap (executes AT the
//            Infinity Cache -> line stays MALL-resident); consumers data-poll with
//            sc0 sc1 loads (bypass L1/L2, served by MALL) until no sentinel dword.
//   Phase 3: out = hs @ W_out^T + b_out                   (bf16 MFMA GEMM)

#define IN_K   512
#define HID    2048
#define OUTN   128
#define BB     8
#define TSTEPS 512
#define NWG    64
#define SENT   0xFF80FF80u

typedef __bf16 bf16x8 __attribute__((ext_vector_type(8)));
typedef unsigned short u16x8 __attribute__((ext_vector_type(8)));
typedef unsigned int u32x4 __attribute__((ext_vector_type(4)));
typedef float f32v4 __attribute__((ext_vector_type(4)));

union Frag8 { u16x8 u; bf16x8 b; u32x4 d; };

__device__ __forceinline__ unsigned short f2bf(float f) {
  unsigned int u = __float_as_uint(f);
  return (unsigned short)((u + 0x7FFFu + ((u >> 16) & 1u)) >> 16);  // RNE
}

__device__ __forceinline__ float tanh_fast(float x) {
  return 1.0f - 2.0f / (__expf(2.0f * x) + 1.0f);  // ~1e-6 abs err, << bf16 rounding
}

// ---------------- Phase 0: sentinel fill (write-through; leaves no dirty L2) ----------------
__global__ __launch_bounds__(256)
void sentinel_kernel(unsigned int* __restrict__ p) {
  const size_t i = ((size_t)blockIdx.x * 256 + threadIdx.x) * 4;
  u32x4 v; v[0] = SENT; v[1] = SENT; v[2] = SENT; v[3] = SENT;
  asm volatile("global_store_dwordx4 %0, %1, off sc0 sc1" :: "v"(p + i), "v"(v) : "memory");
}

// ---------------- GEMM (phases 1 & 3) ----------------
template<int EPI>
__global__ __launch_bounds__(256, 2)
void gemm_kernel(const void* __restrict__ Aptr, const float* __restrict__ Bptr,
                 const float* __restrict__ bias0, const float* __restrict__ bias1,
                 float* __restrict__ Cout, const int Kdim, const int Ndim)
{
  __shared__ __align__(16) unsigned short As[64][56];
  __shared__ __align__(16) unsigned short Bs[64][56];

  const int m0 = blockIdx.x * 64;
  const int n0 = blockIdx.y * 64;
  const int tid = threadIdx.x;
  const int w = tid >> 6, l = tid & 63;
  const int l15 = l & 15, lk = (l >> 4) * 8;
  const int wm = (w >> 1) * 32, wn = (w & 1) * 32;

  f32v4 acc[2][2];
  #pragma unroll
  for (int mt = 0; mt < 2; ++mt)
    #pragma unroll
    for (int nt = 0; nt < 2; ++nt)
      #pragma unroll
      for (int r = 0; r < 4; ++r) acc[mt][nt][r] = 0.0f;

  for (int k0 = 0; k0 < Kdim; k0 += 32) {
    __syncthreads();
    if (EPI == 0) {
      const float* A = (const float*)Aptr;
      const int r = tid >> 3, c4 = (tid & 7) * 4;
      #pragma unroll
      for (int it = 0; it < 2; ++it) {
        const float4 v = *(const float4*)(A + (size_t)(m0 + r + it * 32) * Kdim + k0 + c4);
        unsigned short* d = &As[r + it * 32][c4];
        d[0] = f2bf(v.x); d[1] = f2bf(v.y); d[2] = f2bf(v.z); d[3] = f2bf(v.w);
      }
    } else {
      const unsigned short* A = (const unsigned short*)Aptr;
      const int r = tid >> 2, c8 = (tid & 3) * 8;
      const u16x8 v = *(const u16x8*)(A + (size_t)(m0 + r) * Kdim + k0 + c8);
      *(u16x8*)&As[r][c8] = v;
    }
    {
      const int r = tid >> 3, c4 = (tid & 7) * 4;
      #pragma unroll
      for (int it = 0; it < 2; ++it) {
        const float4 v = *(const float4*)(Bptr + (size_t)(n0 + r + it * 32) * Kdim + k0 + c4);
        unsigned short* d = &Bs[r + it * 32][c4];
        d[0] = f2bf(v.x); d[1] = f2bf(v.y); d[2] = f2bf(v.z); d[3] = f2bf(v.w);
      }
    }
    __syncthreads();

    Frag8 af[2], bg[2];
    #pragma unroll
    for (int mt = 0; mt < 2; ++mt) af[mt].u = *(const u16x8*)&As[wm + mt * 16 + l15][lk];
    #pragma unroll
    for (int nt = 0; nt < 2; ++nt) bg[nt].u = *(const u16x8*)&Bs[wn + nt * 16 + l15][lk];
    #pragma unroll
    for (int mt = 0; mt < 2; ++mt)
      #pragma unroll
      for (int nt = 0; nt < 2; ++nt)
        acc[mt][nt] = __builtin_amdgcn_mfma_f32_16x16x32_bf16(af[mt].b, bg[nt].b, acc[mt][nt], 0, 0, 0);
  }

  #pragma unroll
  for (int mt = 0; mt < 2; ++mt)
    #pragma unroll
    for (int nt = 0; nt < 2; ++nt)
      #pragma unroll
      for (int r = 0; r < 4; ++r) {
        const int m = m0 + wm + mt * 16 + (l >> 4) * 4 + r;
        const int n = n0 + wn + nt * 16 + l15;
        float v = acc[mt][nt][r];
        if (EPI == 0) {
          v += bias0[n] + bias1[n];
          const int b = m >> 9, t = m & 511;
          Cout[((size_t)t * BB + b) * Ndim + n] = v;
        } else {
          v += bias0[n];
          Cout[(size_t)m * Ndim + n] = v;
        }
      }
}

// ---------------- Phase 2: sentinel-dataflow scan, atomic-swap producer stores ----------------
__global__ __launch_bounds__(256, 1)
void scan_kernel(const float* __restrict__ Whh, const float* __restrict__ xp,
                 unsigned short* __restrict__ hs)
{
  const int g = blockIdx.x;
  const int tid = threadIdx.x;
  const int w = tid >> 6, l = tid & 63;     // wave w owns K-chunk [w*512, w*512+512)
  const int l15 = l & 15, lk = (l >> 4) * 8;
  const int jbase = g * 32;                 // wg owns output neurons [jbase, jbase+32)

  // Preload W_hh slice as MFMA B-fragments (128 VGPRs), bf16.
  Frag8 Bw[2][16];
  #pragma unroll
  for (int nt = 0; nt < 2; ++nt) {
    const int j = jbase + nt * 16 + l15;
    #pragma unroll
    for (int kc = 0; kc < 16; ++kc) {
      const int k = w * 512 + kc * 32 + lk;
      const float4* p = (const float4*)(Whh + (size_t)j * HID + k);
      const float4 u0 = p[0], u1 = p[1];
      Frag8 f;
      f.u[0] = f2bf(u0.x); f.u[1] = f2bf(u0.y); f.u[2] = f2bf(u0.z); f.u[3] = f2bf(u0.w);
      f.u[4] = f2bf(u1.x); f.u[5] = f2bf(u1.y); f.u[6] = f2bf(u1.z); f.u[7] = f2bf(u1.w);
      Bw[nt][kc] = f;
    }
  }

  __shared__ float red[2][4][2][16][16];  // double-buffered per-wave partial C tiles, 16KB
  const int om = tid >> 4;             // (tid<128) batch index
  const int oj2 = (tid & 15) * 2;      // thread handles j-offsets oj2, oj2+1
  const int half = oj2 >> 4, col = oj2 & 15;
  const int arow = l15 & 7;            // A rows 8..15 duplicate 0..7 (same addr -> coalesced)

  for (int t = 0; t < TSTEPS; ++t) {
    // xp load (independent of h, normal cached) — overlaps the poll
    float xv0 = 0.f, xv1 = 0.f;
    if (tid < 128) {
      const float2 xv = *(const float2*)(xp + ((size_t)t * BB + om) * HID + jbase + oj2);
      xv0 = xv.x; xv1 = xv.y;
    }

    f32v4 acc0, acc1;
    #pragma unroll
    for (int r = 0; r < 4; ++r) { acc0[r] = 0.f; acc1[r] = 0.f; }

    if (t > 0) {  // h_{-1} == 0
      // data-poll h_{t-1}: sc0 sc1 loads are served at the MALL (producer used atomics)
      const unsigned short* hb = hs + ((size_t)arow * TSTEPS + (t - 1)) * HID + w * 512 + lk;
      Frag8 a[16];
      while (true) {
        #pragma unroll
        for (int kc = 0; kc < 16; ++kc) {
          asm volatile("global_load_dwordx4 %0, %1, off offset:%2 sc0 sc1"
                       : "=v"(a[kc].d) : "v"(hb), "n"(kc * 64));
        }
        asm volatile("s_waitcnt vmcnt(0)" ::: "memory");
        unsigned int mv = 0xFFFFFFFFu;
        #pragma unroll
        for (int kc = 0; kc < 16; ++kc)
          #pragma unroll
          for (int dwi = 0; dwi < 4; ++dwi)
            mv = min(mv, a[kc].d[dwi] ^ SENT);  // ==0 iff that dword is still sentinel
        if (__all(mv != 0u)) break;
      }
      __builtin_amdgcn_sched_barrier(0);  // rule #18: MFMAs stay after the waitcnt/poll
      #pragma unroll
      for (int kc = 0; kc < 16; ++kc) {
        acc0 = __builtin_amdgcn_mfma_f32_16x16x32_bf16(a[kc].b, Bw[0][kc].b, acc0, 0, 0, 0);
        acc1 = __builtin_amdgcn_mfma_f32_16x16x32_bf16(a[kc].b, Bw[1][kc].b, acc1, 0, 0, 0);
      }
    }

    // cross-wave K-reduction via double-buffered LDS (one barrier per step)
    float (*rb)[2][16][16] = red[t & 1];
    #pragma unroll
    for (int r = 0; r < 4; ++r) {
      rb[w][0][(l >> 4) * 4 + r][l15] = acc0[r];
      rb[w][1][(l >> 4) * 4 + r][l15] = acc1[r];
    }
    __syncthreads();

    if (tid < 128) {
      float s0 = rb[0][half][om][col]     + rb[1][half][om][col]
               + rb[2][half][om][col]     + rb[3][half][om][col]     + xv0;
      float s1 = rb[0][half][om][col + 1] + rb[1][half][om][col + 1]
               + rb[2][half][om][col + 1] + rb[3][half][om][col + 1] + xv1;
      const float h0 = tanh_fast(s0), h1 = tanh_fast(s1);
      const unsigned int packed = (unsigned int)f2bf(h0) | ((unsigned int)f2bf(h1) << 16);
      // exchange store: non-returning atomic swap executes AT the MALL -> line stays resident
      unsigned int* hp = (unsigned int*)(hs + ((size_t)om * TSTEPS + t) * HID + jbase + oj2);
      __hip_atomic_exchange(hp, packed, __ATOMIC_RELAXED, __HIP_MEMORY_SCOPE_AGENT);
    }
    // no trailing syncthreads: red[] is double-buffered; next write targets the other buffer
  }
}

extern "C" void kernel_launch(void* const* d_in, const int* in_sizes, int n_in,
                              void* d_out, int out_size, void* d_ws, size_t ws_size,
                              hipStream_t stream)
{
  (void)in_sizes; (void)n_in; (void)out_size; (void)ws_size;
  const float* x    = (const float*)d_in[0];
  const float* Wih  = (const float*)d_in[1];
  const float* bih  = (const float*)d_in[2];
  const float* Whh  = (const float*)d_in[3];
  const float* bhh  = (const float*)d_in[4];
  const float* Wout = (const float*)d_in[5];
  const float* bout = (const float*)d_in[6];
  float* out = (float*)d_out;

  char* ws = (char*)d_ws;
  float* xp          = (float*)(ws);                                // [512][8][2048] fp32, 32 MiB
  unsigned short* hs = (unsigned short*)(ws + (size_t)(32 << 20));  // [8][512][2048] bf16, 16 MiB

  // Phase 0: sentinel-fill hs (write-through; 16 MiB / 16 B = 1,048,576 stores)
  sentinel_kernel<<<dim3(4096), 256, 0, stream>>>((unsigned int*)hs);
  // Phase 1: xp = x @ W_ih^T + b_ih + b_hh
  gemm_kernel<0><<<dim3(64, 32), 256, 0, stream>>>(x, Wih, bih, bhh, xp, IN_K, HID);
  // Phase 2: barrier-free sequential scan
  scan_kernel<<<dim3(NWG), 256, 0, stream>>>(Whh, xp, hs);
  // Phase 3: out = hs @ W_out^T + b_out
  gemm_kernel<1><<<dim3(64, 2), 256, 0, stream>>>(hs, Wout, bout, nullptr, out, HID, OUTN);
}

// Round 8
// 2334.095 us; speedup vs baseline: 1.1573x; 1.0182x over previous
//
#include <hip/hip_runtime.h>

// zhannRNN: x[8,512,512] -> xp GEMM -> 512-step tanh recurrence (HID=2048) -> out GEMM [*,128]
//   Phase 0: fill hs with sentinel 0xFF80FF80 (-Inf bf16; impossible as tanh output)
//   Phase 1: xp[t][b][j] = x @ W_ih^T + b_ih + b_hh      (bf16 MFMA GEMM)
//   Phase 2: persistent scan, 64 wgs x 256 thr (R3 structure), W_hh register-resident
//            (asm keep-alive; 4-wave wg tolerates up to 512 VGPR -> always schedulable).
//            Exchange: relaxed agent WT stores; consumers data-poll sc0 sc1 until no
//            sentinel dword (store IS the signal, no barrier).
//   Phase 3: out = hs @ W_out^T + b_out                   (bf16 MFMA GEMM)

#define IN_K   512
#define HID    2048
#define OUTN   128
#define BB     8
#define TSTEPS 512
#define NWG    64
#define SENT   0xFF80FF80u

typedef __bf16 bf16x8 __attribute__((ext_vector_type(8)));
typedef unsigned short u16x8 __attribute__((ext_vector_type(8)));
typedef unsigned int u32x4 __attribute__((ext_vector_type(4)));
typedef float f32v4 __attribute__((ext_vector_type(4)));

union Frag8 { u16x8 u; bf16x8 b; u32x4 d; };

__device__ __forceinline__ unsigned short f2bf(float f) {
  unsigned int u = __float_as_uint(f);
  return (unsigned short)((u + 0x7FFFu + ((u >> 16) & 1u)) >> 16);  // RNE
}

__device__ __forceinline__ float tanh_fast(float x) {
  return 1.0f - 2.0f / (__expf(2.0f * x) + 1.0f);  // ~1e-6 abs err, << bf16 rounding
}

// ---------------- Phase 0: sentinel fill ----------------
__global__ __launch_bounds__(256)
void sentinel_kernel(u32x4* __restrict__ p) {
  const size_t i = (size_t)blockIdx.x * 256 + threadIdx.x;
  u32x4 v; v[0] = SENT; v[1] = SENT; v[2] = SENT; v[3] = SENT;
  p[i] = v;
}

// ---------------- GEMM (phases 1 & 3) ----------------
template<int EPI>
__global__ __launch_bounds__(256, 2)
void gemm_kernel(const void* __restrict__ Aptr, const float* __restrict__ Bptr,
                 const float* __restrict__ bias0, const float* __restrict__ bias1,
                 float* __restrict__ Cout, const int Kdim, const int Ndim)
{
  __shared__ __align__(16) unsigned short As[64][56];
  __shared__ __align__(16) unsigned short Bs[64][56];

  const int m0 = blockIdx.x * 64;
  const int n0 = blockIdx.y * 64;
  const int tid = threadIdx.x;
  const int w = tid >> 6, l = tid & 63;
  const int l15 = l & 15, lk = (l >> 4) * 8;
  const int wm = (w >> 1) * 32, wn = (w & 1) * 32;

  f32v4 acc[2][2];
  #pragma unroll
  for (int mt = 0; mt < 2; ++mt)
    #pragma unroll
    for (int nt = 0; nt < 2; ++nt)
      #pragma unroll
      for (int r = 0; r < 4; ++r) acc[mt][nt][r] = 0.0f;

  for (int k0 = 0; k0 < Kdim; k0 += 32) {
    __syncthreads();
    if (EPI == 0) {
      const float* A = (const float*)Aptr;
      const int r = tid >> 3, c4 = (tid & 7) * 4;
      #pragma unroll
      for (int it = 0; it < 2; ++it) {
        const float4 v = *(const float4*)(A + (size_t)(m0 + r + it * 32) * Kdim + k0 + c4);
        unsigned short* d = &As[r + it * 32][c4];
        d[0] = f2bf(v.x); d[1] = f2bf(v.y); d[2] = f2bf(v.z); d[3] = f2bf(v.w);
      }
    } else {
      const unsigned short* A = (const unsigned short*)Aptr;
      const int r = tid >> 2, c8 = (tid & 3) * 8;
      const u16x8 v = *(const u16x8*)(A + (size_t)(m0 + r) * Kdim + k0 + c8);
      *(u16x8*)&As[r][c8] = v;
    }
    {
      const int r = tid >> 3, c4 = (tid & 7) * 4;
      #pragma unroll
      for (int it = 0; it < 2; ++it) {
        const float4 v = *(const float4*)(Bptr + (size_t)(n0 + r + it * 32) * Kdim + k0 + c4);
        unsigned short* d = &Bs[r + it * 32][c4];
        d[0] = f2bf(v.x); d[1] = f2bf(v.y); d[2] = f2bf(v.z); d[3] = f2bf(v.w);
      }
    }
    __syncthreads();

    Frag8 af[2], bg[2];
    #pragma unroll
    for (int mt = 0; mt < 2; ++mt) af[mt].u = *(const u16x8*)&As[wm + mt * 16 + l15][lk];
    #pragma unroll
    for (int nt = 0; nt < 2; ++nt) bg[nt].u = *(const u16x8*)&Bs[wn + nt * 16 + l15][lk];
    #pragma unroll
    for (int mt = 0; mt < 2; ++mt)
      #pragma unroll
      for (int nt = 0; nt < 2; ++nt)
        acc[mt][nt] = __builtin_amdgcn_mfma_f32_16x16x32_bf16(af[mt].b, bg[nt].b, acc[mt][nt], 0, 0, 0);
  }

  #pragma unroll
  for (int mt = 0; mt < 2; ++mt)
    #pragma unroll
    for (int nt = 0; nt < 2; ++nt)
      #pragma unroll
      for (int r = 0; r < 4; ++r) {
        const int m = m0 + wm + mt * 16 + (l >> 4) * 4 + r;
        const int n = n0 + wn + nt * 16 + l15;
        float v = acc[mt][nt][r];
        if (EPI == 0) {
          v += bias0[n] + bias1[n];
          const int b = m >> 9, t = m & 511;
          Cout[((size_t)t * BB + b) * Ndim + n] = v;
        } else {
          v += bias0[n];
          Cout[(size_t)m * Ndim + n] = v;
        }
      }
}

// ---------------- Phase 2: sentinel-dataflow scan, W register-resident ----------------
__global__ __launch_bounds__(256, 1)
void scan_kernel(const float* __restrict__ Whh, const float* __restrict__ xp,
                 unsigned short* __restrict__ hs)
{
  const int g = blockIdx.x;
  const int tid = threadIdx.x;
  const int w = tid >> 6, l = tid & 63;     // wave w owns K-chunk [w*512, w*512+512)
  const int l15 = l & 15, lk = (l >> 4) * 8;
  const int jbase = g * 32;                 // wg owns output neurons [jbase, jbase+32)

  // Preload W_hh slice as MFMA B-fragments (128 VGPRs), bf16.
  Frag8 Bw[2][16];
  #pragma unroll
  for (int nt = 0; nt < 2; ++nt) {
    const int j = jbase + nt * 16 + l15;
    #pragma unroll
    for (int kc = 0; kc < 16; ++kc) {
      const int k = w * 512 + kc * 32 + lk;
      const float4* p = (const float4*)(Whh + (size_t)j * HID + k);
      const float4 u0 = p[0], u1 = p[1];
      Frag8 f;
      f.u[0] = f2bf(u0.x); f.u[1] = f2bf(u0.y); f.u[2] = f2bf(u0.z); f.u[3] = f2bf(u0.w);
      f.u[4] = f2bf(u1.x); f.u[5] = f2bf(u1.y); f.u[6] = f2bf(u1.z); f.u[7] = f2bf(u1.w);
      Bw[nt][kc] = f;
    }
  }
  // keep-alive: opaque asm def forbids rematerialization -> W must stay in registers
  #pragma unroll
  for (int nt = 0; nt < 2; ++nt)
    #pragma unroll
    for (int kc = 0; kc < 16; ++kc)
      asm volatile("" : "+v"(Bw[nt][kc].d));

  __shared__ float red[2][4][2][16][16];  // double-buffered per-wave partial C tiles, 16KB
  const int om = tid >> 4;             // (tid<128) batch index
  const int oj2 = (tid & 15) * 2;      // thread handles j-offsets oj2, oj2+1
  const int half = oj2 >> 4, col = oj2 & 15;
  const int arow = l15 & 7;            // A rows 8..15 duplicate 0..7 (same addr -> coalesced)

  for (int t = 0; t < TSTEPS; ++t) {
    // xp load (independent of h, cached) — overlaps the poll
    float xv0 = 0.f, xv1 = 0.f;
    if (tid < 128) {
      const float2 xv = *(const float2*)(xp + ((size_t)t * BB + om) * HID + jbase + oj2);
      xv0 = xv.x; xv1 = xv.y;
    }

    f32v4 acc0, acc1;
    #pragma unroll
    for (int r = 0; r < 4; ++r) { acc0[r] = 0.f; acc1[r] = 0.f; }

    if (t > 0) {  // h_{-1} == 0
      // data-poll h_{t-1} through the coherence point until no sentinel dword
      const unsigned short* hb = hs + ((size_t)arow * TSTEPS + (t - 1)) * HID + w * 512 + lk;
      Frag8 a[16];
      while (true) {
        #pragma unroll
        for (int kc = 0; kc < 16; ++kc) {
          asm volatile("global_load_dwordx4 %0, %1, off offset:%2 sc0 sc1"
                       : "=v"(a[kc].d) : "v"(hb), "n"(kc * 64));
        }
        asm volatile("s_waitcnt vmcnt(0)" ::: "memory");
        unsigned int mv = 0xFFFFFFFFu;
        #pragma unroll
        for (int kc = 0; kc < 16; ++kc)
          #pragma unroll
          for (int dwi = 0; dwi < 4; ++dwi)
            mv = min(mv, a[kc].d[dwi] ^ SENT);  // ==0 iff that dword is still sentinel
        if (__all(mv != 0u)) break;
      }
      __builtin_amdgcn_sched_barrier(0);  // rule #18: MFMAs stay after the waitcnt/poll
      #pragma unroll
      for (int kc = 0; kc < 16; ++kc) {
        acc0 = __builtin_amdgcn_mfma_f32_16x16x32_bf16(a[kc].b, Bw[0][kc].b, acc0, 0, 0, 0);
        acc1 = __builtin_amdgcn_mfma_f32_16x16x32_bf16(a[kc].b, Bw[1][kc].b, acc1, 0, 0, 0);
      }
    }

    // cross-wave K-reduction via double-buffered LDS (one barrier per step)
    float (*rb)[2][16][16] = red[t & 1];
    #pragma unroll
    for (int r = 0; r < 4; ++r) {
      rb[w][0][(l >> 4) * 4 + r][l15] = acc0[r];
      rb[w][1][(l >> 4) * 4 + r][l15] = acc1[r];
    }
    __syncthreads();

    if (tid < 128) {
      float s0 = rb[0][half][om][col]     + rb[1][half][om][col]
               + rb[2][half][om][col]     + rb[3][half][om][col]     + xv0;
      float s1 = rb[0][half][om][col + 1] + rb[1][half][om][col + 1]
               + rb[2][half][om][col + 1] + rb[3][half][om][col + 1] + xv1;
      const float h0 = tanh_fast(s0), h1 = tanh_fast(s1);
      const unsigned int packed = (unsigned int)f2bf(h0) | ((unsigned int)f2bf(h1) << 16);
      // the signal: relaxed agent write-through store into the unique per-step slice
      unsigned int* hp = (unsigned int*)(hs + ((size_t)om * TSTEPS + t) * HID + jbase + oj2);
      __hip_atomic_store(hp, packed, __ATOMIC_RELAXED, __HIP_MEMORY_SCOPE_AGENT);
    }
    // no trailing barrier: red[] double-buffered
  }
}

extern "C" void kernel_launch(void* const* d_in, const int* in_sizes, int n_in,
                              void* d_out, int out_size, void* d_ws, size_t ws_size,
                              hipStream_t stream)
{
  (void)in_sizes; (void)n_in; (void)out_size; (void)ws_size;
  const float* x    = (const float*)d_in[0];
  const float* Wih  = (const float*)d_in[1];
  const float* bih  = (const float*)d_in[2];
  const float* Whh  = (const float*)d_in[3];
  const float* bhh  = (const float*)d_in[4];
  const float* Wout = (const float*)d_in[5];
  const float* bout = (const float*)d_in[6];
  float* out = (float*)d_out;

  char* ws = (char*)d_ws;
  float* xp          = (float*)(ws);                                // [512][8][2048] fp32, 32 MiB
  unsigned short* hs = (unsigned short*)(ws + (size_t)(32 << 20));  // [8][512][2048] bf16, 16 MiB

  // Phase 0: sentinel-fill hs
  sentinel_kernel<<<dim3(4096), 256, 0, stream>>>((u32x4*)hs);
  // Phase 1: xp = x @ W_ih^T + b_ih + b_hh
  gemm_kernel<0><<<dim3(64, 32), 256, 0, stream>>>(x, Wih, bih, bhh, xp, IN_K, HID);
  // Phase 2: barrier-free sequential scan (W register-resident)
  scan_kernel<<<dim3(NWG), 256, 0, stream>>>(Whh, xp, hs);
  // Phase 3: out = hs @ W_out^T + b_out
  gemm_kernel<1><<<dim3(64, 2), 256, 0, stream>>>(hs, Wout, bout, nullptr, out, HID, OUTN);
}

// Round 9
// 1819.522 us; speedup vs baseline: 1.4846x; 1.2828x over previous
//
#include <hip/hip_runtime.h>

// zhannRNN: x[8,512,512] -> xp GEMM -> 512-step tanh recurrence (HID=2048) -> out GEMM [*,128]
//   Phase 0: fill hs with sentinel 0xFF80FF80 (-Inf bf16; impossible as tanh output)
//   Phase 1: xp[t][b][j] = x @ W_ih^T + b_ih + b_hh      (bf16 MFMA GEMM)
//   Phase 2: persistent scan, 64 wgs x 256 thr (R3 structure). Exchange: relaxed agent
//            WT stores; consumers SELECTIVELY re-poll only not-yet-valid fragments and
//            MFMA each fragment the moment it becomes valid (overlap wait with compute).
//   Phase 3: out = hs @ W_out^T + b_out                   (bf16 MFMA GEMM)

#define IN_K   512
#define HID    2048
#define OUTN   128
#define BB     8
#define TSTEPS 512
#define NWG    64
#define SENT   0xFF80FF80u

typedef __bf16 bf16x8 __attribute__((ext_vector_type(8)));
typedef unsigned short u16x8 __attribute__((ext_vector_type(8)));
typedef unsigned int u32x4 __attribute__((ext_vector_type(4)));
typedef float f32v4 __attribute__((ext_vector_type(4)));

union Frag8 { u16x8 u; bf16x8 b; u32x4 d; };

__device__ __forceinline__ unsigned short f2bf(float f) {
  unsigned int u = __float_as_uint(f);
  return (unsigned short)((u + 0x7FFFu + ((u >> 16) & 1u)) >> 16);  // RNE
}

__device__ __forceinline__ float tanh_fast(float x) {
  return 1.0f - 2.0f / (__expf(2.0f * x) + 1.0f);  // ~1e-6 abs err, << bf16 rounding
}

// ---------------- Phase 0: sentinel fill ----------------
__global__ __launch_bounds__(256)
void sentinel_kernel(u32x4* __restrict__ p) {
  const size_t i = (size_t)blockIdx.x * 256 + threadIdx.x;
  u32x4 v; v[0] = SENT; v[1] = SENT; v[2] = SENT; v[3] = SENT;
  p[i] = v;
}

// ---------------- GEMM (phases 1 & 3) ----------------
template<int EPI>
__global__ __launch_bounds__(256, 2)
void gemm_kernel(const void* __restrict__ Aptr, const float* __restrict__ Bptr,
                 const float* __restrict__ bias0, const float* __restrict__ bias1,
                 float* __restrict__ Cout, const int Kdim, const int Ndim)
{
  __shared__ __align__(16) unsigned short As[64][56];
  __shared__ __align__(16) unsigned short Bs[64][56];

  const int m0 = blockIdx.x * 64;
  const int n0 = blockIdx.y * 64;
  const int tid = threadIdx.x;
  const int w = tid >> 6, l = tid & 63;
  const int l15 = l & 15, lk = (l >> 4) * 8;
  const int wm = (w >> 1) * 32, wn = (w & 1) * 32;

  f32v4 acc[2][2];
  #pragma unroll
  for (int mt = 0; mt < 2; ++mt)
    #pragma unroll
    for (int nt = 0; nt < 2; ++nt)
      #pragma unroll
      for (int r = 0; r < 4; ++r) acc[mt][nt][r] = 0.0f;

  for (int k0 = 0; k0 < Kdim; k0 += 32) {
    __syncthreads();
    if (EPI == 0) {
      const float* A = (const float*)Aptr;
      const int r = tid >> 3, c4 = (tid & 7) * 4;
      #pragma unroll
      for (int it = 0; it < 2; ++it) {
        const float4 v = *(const float4*)(A + (size_t)(m0 + r + it * 32) * Kdim + k0 + c4);
        unsigned short* d = &As[r + it * 32][c4];
        d[0] = f2bf(v.x); d[1] = f2bf(v.y); d[2] = f2bf(v.z); d[3] = f2bf(v.w);
      }
    } else {
      const unsigned short* A = (const unsigned short*)Aptr;
      const int r = tid >> 2, c8 = (tid & 3) * 8;
      const u16x8 v = *(const u16x8*)(A + (size_t)(m0 + r) * Kdim + k0 + c8);
      *(u16x8*)&As[r][c8] = v;
    }
    {
      const int r = tid >> 3, c4 = (tid & 7) * 4;
      #pragma unroll
      for (int it = 0; it < 2; ++it) {
        const float4 v = *(const float4*)(Bptr + (size_t)(n0 + r + it * 32) * Kdim + k0 + c4);
        unsigned short* d = &Bs[r + it * 32][c4];
        d[0] = f2bf(v.x); d[1] = f2bf(v.y); d[2] = f2bf(v.z); d[3] = f2bf(v.w);
      }
    }
    __syncthreads();

    Frag8 af[2], bg[2];
    #pragma unroll
    for (int mt = 0; mt < 2; ++mt) af[mt].u = *(const u16x8*)&As[wm + mt * 16 + l15][lk];
    #pragma unroll
    for (int nt = 0; nt < 2; ++nt) bg[nt].u = *(const u16x8*)&Bs[wn + nt * 16 + l15][lk];
    #pragma unroll
    for (int mt = 0; mt < 2; ++mt)
      #pragma unroll
      for (int nt = 0; nt < 2; ++nt)
        acc[mt][nt] = __builtin_amdgcn_mfma_f32_16x16x32_bf16(af[mt].b, bg[nt].b, acc[mt][nt], 0, 0, 0);
  }

  #pragma unroll
  for (int mt = 0; mt < 2; ++mt)
    #pragma unroll
    for (int nt = 0; nt < 2; ++nt)
      #pragma unroll
      for (int r = 0; r < 4; ++r) {
        const int m = m0 + wm + mt * 16 + (l >> 4) * 4 + r;
        const int n = n0 + wn + nt * 16 + l15;
        float v = acc[mt][nt][r];
        if (EPI == 0) {
          v += bias0[n] + bias1[n];
          const int b = m >> 9, t = m & 511;
          Cout[((size_t)t * BB + b) * Ndim + n] = v;
        } else {
          v += bias0[n];
          Cout[(size_t)m * Ndim + n] = v;
        }
      }
}

// ---------------- Phase 2: sentinel scan with selective re-poll + incremental MFMA ----------------
__global__ __launch_bounds__(256, 1)
void scan_kernel(const float* __restrict__ Whh, const float* __restrict__ xp,
                 unsigned short* __restrict__ hs)
{
  const int g = blockIdx.x;
  const int tid = threadIdx.x;
  const int w = tid >> 6, l = tid & 63;     // wave w owns K-chunk [w*512, w*512+512)
  const int l15 = l & 15, lk = (l >> 4) * 8;
  const int jbase = g * 32;                 // wg owns output neurons [jbase, jbase+32)

  // Preload W_hh slice as MFMA B-fragments, bf16.
  Frag8 Bw[2][16];
  #pragma unroll
  for (int nt = 0; nt < 2; ++nt) {
    const int j = jbase + nt * 16 + l15;
    #pragma unroll
    for (int kc = 0; kc < 16; ++kc) {
      const int k = w * 512 + kc * 32 + lk;
      const float4* p = (const float4*)(Whh + (size_t)j * HID + k);
      const float4 u0 = p[0], u1 = p[1];
      Frag8 f;
      f.u[0] = f2bf(u0.x); f.u[1] = f2bf(u0.y); f.u[2] = f2bf(u0.z); f.u[3] = f2bf(u0.w);
      f.u[4] = f2bf(u1.x); f.u[5] = f2bf(u1.y); f.u[6] = f2bf(u1.z); f.u[7] = f2bf(u1.w);
      Bw[nt][kc] = f;
    }
  }

  __shared__ float red[4][2][16][16];  // per-wave partial C tiles, 8KB
  const int om = tid >> 4;             // (tid<128) batch index
  const int oj2 = (tid & 15) * 2;      // thread handles j-offsets oj2, oj2+1
  const int half = oj2 >> 4, col = oj2 & 15;
  const int arow = l15 & 7;            // A rows 8..15 duplicate 0..7 (same addr -> coalesced)

  for (int t = 0; t < TSTEPS; ++t) {
    // xp load (independent of h, cached) — overlaps the poll
    float xv0 = 0.f, xv1 = 0.f;
    if (tid < 128) {
      const float2 xv = *(const float2*)(xp + ((size_t)t * BB + om) * HID + jbase + oj2);
      xv0 = xv.x; xv1 = xv.y;
    }

    f32v4 acc0, acc1;
    #pragma unroll
    for (int r = 0; r < 4; ++r) { acc0[r] = 0.f; acc1[r] = 0.f; }

    if (t > 0) {  // h_{-1} == 0
      const unsigned short* hb = hs + ((size_t)arow * TSTEPS + (t - 1)) * HID + w * 512 + lk;
      Frag8 a[16];
      unsigned int valid = 0;  // wave-uniform bitmask of sentinel-free fragments
      do {
        // (re)issue loads ONLY for not-yet-valid fragments
        #pragma unroll
        for (int kc = 0; kc < 16; ++kc) {
          if (!(valid & (1u << kc))) {
            asm volatile("global_load_dwordx4 %0, %1, off offset:%2 sc0 sc1"
                         : "=v"(a[kc].d) : "v"(hb), "n"(kc * 64));
          }
        }
        asm volatile("s_waitcnt vmcnt(0)" ::: "memory");
        __builtin_amdgcn_sched_barrier(0);  // rule #18: checks must not hoist above the wait
        // validate each pending fragment; MFMA it the moment it is complete
        #pragma unroll
        for (int kc = 0; kc < 16; ++kc) {
          if (!(valid & (1u << kc))) {
            unsigned int mv = min(min(a[kc].d[0] ^ SENT, a[kc].d[1] ^ SENT),
                                  min(a[kc].d[2] ^ SENT, a[kc].d[3] ^ SENT));
            if (__all(mv != 0u)) {
              valid |= (1u << kc);
              acc0 = __builtin_amdgcn_mfma_f32_16x16x32_bf16(a[kc].b, Bw[0][kc].b, acc0, 0, 0, 0);
              acc1 = __builtin_amdgcn_mfma_f32_16x16x32_bf16(a[kc].b, Bw[1][kc].b, acc1, 0, 0, 0);
            }
          }
        }
      } while (valid != 0xFFFFu);
    }

    // cross-wave K-reduction via LDS
    #pragma unroll
    for (int r = 0; r < 4; ++r) {
      red[w][0][(l >> 4) * 4 + r][l15] = acc0[r];
      red[w][1][(l >> 4) * 4 + r][l15] = acc1[r];
    }
    __syncthreads();

    if (tid < 128) {
      float s0 = red[0][half][om][col]     + red[1][half][om][col]
               + red[2][half][om][col]     + red[3][half][om][col]     + xv0;
      float s1 = red[0][half][om][col + 1] + red[1][half][om][col + 1]
               + red[2][half][om][col + 1] + red[3][half][om][col + 1] + xv1;
      const float h0 = tanh_fast(s0), h1 = tanh_fast(s1);
      const unsigned int packed = (unsigned int)f2bf(h0) | ((unsigned int)f2bf(h1) << 16);
      // the signal: relaxed agent write-through store into the unique per-step slice
      unsigned int* hp = (unsigned int*)(hs + ((size_t)om * TSTEPS + t) * HID + jbase + oj2);
      __hip_atomic_store(hp, packed, __ATOMIC_RELAXED, __HIP_MEMORY_SCOPE_AGENT);
    }
    __syncthreads();  // red[] reuse discipline for next step
  }
}

extern "C" void kernel_launch(void* const* d_in, const int* in_sizes, int n_in,
                              void* d_out, int out_size, void* d_ws, size_t ws_size,
                              hipStream_t stream)
{
  (void)in_sizes; (void)n_in; (void)out_size; (void)ws_size;
  const float* x    = (const float*)d_in[0];
  const float* Wih  = (const float*)d_in[1];
  const float* bih  = (const float*)d_in[2];
  const float* Whh  = (const float*)d_in[3];
  const float* bhh  = (const float*)d_in[4];
  const float* Wout = (const float*)d_in[5];
  const float* bout = (const float*)d_in[6];
  float* out = (float*)d_out;

  char* ws = (char*)d_ws;
  float* xp          = (float*)(ws);                                // [512][8][2048] fp32, 32 MiB
  unsigned short* hs = (unsigned short*)(ws + (size_t)(32 << 20));  // [8][512][2048] bf16, 16 MiB

  // Phase 0: sentinel-fill hs
  sentinel_kernel<<<dim3(4096), 256, 0, stream>>>((u32x4*)hs);
  // Phase 1: xp = x @ W_ih^T + b_ih + b_hh
  gemm_kernel<0><<<dim3(64, 32), 256, 0, stream>>>(x, Wih, bih, bhh, xp, IN_K, HID);
  // Phase 2: barrier-free sequential scan (selective re-poll)
  scan_kernel<<<dim3(NWG), 256, 0, stream>>>(Whh, xp, hs);
  // Phase 3: out = hs @ W_out^T + b_out
  gemm_kernel<1><<<dim3(64, 2), 256, 0, stream>>>(hs, Wout, bout, nullptr, out, HID, OUTN);
}

// Round 10
// 1819.432 us; speedup vs baseline: 1.4846x; 1.0000x over previous
//
#include <hip/hip_runtime.h>

// zhannRNN: x[8,512,512] -> xp GEMM -> 512-step tanh recurrence (HID=2048) -> out GEMM [*,128]
//   Phase 0: fill hs with sentinel 0xFF80FF80 (-Inf bf16; impossible as tanh output)
//   Phase 1: xp[t][b][j] = x @ W_ih^T + b_ih + b_hh      (bf16 MFMA GEMM)
//   Phase 2: persistent scan, 32 wgs x 512 thr (8 waves; wave k-chunk 256; wg j-width 64).
//            Fan-in per consumer wave = 4 producer wgs (was 16). R9 protocol: sentinel
//            data-poll, selective per-fragment re-poll, incremental MFMA on arrival.
//   Phase 3: out = hs @ W_out^T + b_out                   (bf16 MFMA GEMM)

#define IN_K   512
#define HID    2048
#define OUTN   128
#define BB     8
#define TSTEPS 512
#define NWG    32
#define JPW    64
#define SENT   0xFF80FF80u

typedef __bf16 bf16x8 __attribute__((ext_vector_type(8)));
typedef unsigned short u16x8 __attribute__((ext_vector_type(8)));
typedef unsigned int u32x4 __attribute__((ext_vector_type(4)));
typedef float f32v4 __attribute__((ext_vector_type(4)));

union Frag8 { u16x8 u; bf16x8 b; u32x4 d; };

__device__ __forceinline__ unsigned short f2bf(float f) {
  unsigned int u = __float_as_uint(f);
  return (unsigned short)((u + 0x7FFFu + ((u >> 16) & 1u)) >> 16);  // RNE
}

__device__ __forceinline__ float tanh_fast(float x) {
  return 1.0f - 2.0f / (__expf(2.0f * x) + 1.0f);  // ~1e-6 abs err, << bf16 rounding
}

// ---------------- Phase 0: sentinel fill ----------------
__global__ __launch_bounds__(256)
void sentinel_kernel(u32x4* __restrict__ p) {
  const size_t i = (size_t)blockIdx.x * 256 + threadIdx.x;
  u32x4 v; v[0] = SENT; v[1] = SENT; v[2] = SENT; v[3] = SENT;
  p[i] = v;
}

// ---------------- GEMM (phases 1 & 3) ----------------
template<int EPI>
__global__ __launch_bounds__(256, 2)
void gemm_kernel(const void* __restrict__ Aptr, const float* __restrict__ Bptr,
                 const float* __restrict__ bias0, const float* __restrict__ bias1,
                 float* __restrict__ Cout, const int Kdim, const int Ndim)
{
  __shared__ __align__(16) unsigned short As[64][56];
  __shared__ __align__(16) unsigned short Bs[64][56];

  const int m0 = blockIdx.x * 64;
  const int n0 = blockIdx.y * 64;
  const int tid = threadIdx.x;
  const int w = tid >> 6, l = tid & 63;
  const int l15 = l & 15, lk = (l >> 4) * 8;
  const int wm = (w >> 1) * 32, wn = (w & 1) * 32;

  f32v4 acc[2][2];
  #pragma unroll
  for (int mt = 0; mt < 2; ++mt)
    #pragma unroll
    for (int nt = 0; nt < 2; ++nt)
      #pragma unroll
      for (int r = 0; r < 4; ++r) acc[mt][nt][r] = 0.0f;

  for (int k0 = 0; k0 < Kdim; k0 += 32) {
    __syncthreads();
    if (EPI == 0) {
      const float* A = (const float*)Aptr;
      const int r = tid >> 3, c4 = (tid & 7) * 4;
      #pragma unroll
      for (int it = 0; it < 2; ++it) {
        const float4 v = *(const float4*)(A + (size_t)(m0 + r + it * 32) * Kdim + k0 + c4);
        unsigned short* d = &As[r + it * 32][c4];
        d[0] = f2bf(v.x); d[1] = f2bf(v.y); d[2] = f2bf(v.z); d[3] = f2bf(v.w);
      }
    } else {
      const unsigned short* A = (const unsigned short*)Aptr;
      const int r = tid >> 2, c8 = (tid & 3) * 8;
      const u16x8 v = *(const u16x8*)(A + (size_t)(m0 + r) * Kdim + k0 + c8);
      *(u16x8*)&As[r][c8] = v;
    }
    {
      const int r = tid >> 3, c4 = (tid & 7) * 4;
      #pragma unroll
      for (int it = 0; it < 2; ++it) {
        const float4 v = *(const float4*)(Bptr + (size_t)(n0 + r + it * 32) * Kdim + k0 + c4);
        unsigned short* d = &Bs[r + it * 32][c4];
        d[0] = f2bf(v.x); d[1] = f2bf(v.y); d[2] = f2bf(v.z); d[3] = f2bf(v.w);
      }
    }
    __syncthreads();

    Frag8 af[2], bg[2];
    #pragma unroll
    for (int mt = 0; mt < 2; ++mt) af[mt].u = *(const u16x8*)&As[wm + mt * 16 + l15][lk];
    #pragma unroll
    for (int nt = 0; nt < 2; ++nt) bg[nt].u = *(const u16x8*)&Bs[wn + nt * 16 + l15][lk];
    #pragma unroll
    for (int mt = 0; mt < 2; ++mt)
      #pragma unroll
      for (int nt = 0; nt < 2; ++nt)
        acc[mt][nt] = __builtin_amdgcn_mfma_f32_16x16x32_bf16(af[mt].b, bg[nt].b, acc[mt][nt], 0, 0, 0);
  }

  #pragma unroll
  for (int mt = 0; mt < 2; ++mt)
    #pragma unroll
    for (int nt = 0; nt < 2; ++nt)
      #pragma unroll
      for (int r = 0; r < 4; ++r) {
        const int m = m0 + wm + mt * 16 + (l >> 4) * 4 + r;
        const int n = n0 + wn + nt * 16 + l15;
        float v = acc[mt][nt][r];
        if (EPI == 0) {
          v += bias0[n] + bias1[n];
          const int b = m >> 9, t = m & 511;
          Cout[((size_t)t * BB + b) * Ndim + n] = v;
        } else {
          v += bias0[n];
          Cout[(size_t)m * Ndim + n] = v;
        }
      }
}

// ---------------- Phase 2: 32wg x 8-wave sentinel scan, selective re-poll ----------------
__global__ __launch_bounds__(512, 2)
void scan_kernel(const float* __restrict__ Whh, const float* __restrict__ xp,
                 unsigned short* __restrict__ hs)
{
  const int g = blockIdx.x;
  const int tid = threadIdx.x;
  const int w = tid >> 6, l = tid & 63;     // wave w in [0,8): K-chunk [w*256, w*256+256)
  const int l15 = l & 15, lk = (l >> 4) * 8;
  const int jbase = g * JPW;                // wg owns j in [jbase, jbase+64)

  // Preload W_hh slice: Bw[jt][kc], j = jbase+jt*16+l15, k = w*256+kc*32+lk  (128 VGPRs)
  Frag8 Bw[4][8];
  #pragma unroll
  for (int jt = 0; jt < 4; ++jt) {
    const int j = jbase + jt * 16 + l15;
    #pragma unroll
    for (int kc = 0; kc < 8; ++kc) {
      const int k = w * 256 + kc * 32 + lk;
      const float4* p = (const float4*)(Whh + (size_t)j * HID + k);
      const float4 u0 = p[0], u1 = p[1];
      Frag8 f;
      f.u[0] = f2bf(u0.x); f.u[1] = f2bf(u0.y); f.u[2] = f2bf(u0.z); f.u[3] = f2bf(u0.w);
      f.u[4] = f2bf(u1.x); f.u[5] = f2bf(u1.y); f.u[6] = f2bf(u1.z); f.u[7] = f2bf(u1.w);
      Bw[jt][kc] = f;
    }
  }

  __shared__ float red[8][4][16][16];  // 8 waves x 4 j-tiles x 16x16, 32KB
  const int om = tid >> 5;             // (tid<256) batch index
  const int oj2 = (tid & 31) * 2;      // j-offset pair within wg
  const int jt_e = oj2 >> 4, col = oj2 & 15;
  const int arow = l15 & 7;            // A rows 8..15 duplicate 0..7 (same addr -> coalesced)

  for (int t = 0; t < TSTEPS; ++t) {
    // xp load (independent of h, cached) — overlaps the poll
    float xv0 = 0.f, xv1 = 0.f;
    if (tid < 256) {
      const float2 xv = *(const float2*)(xp + ((size_t)t * BB + om) * HID + jbase + oj2);
      xv0 = xv.x; xv1 = xv.y;
    }

    f32v4 acc[4];
    #pragma unroll
    for (int jt = 0; jt < 4; ++jt)
      #pragma unroll
      for (int r = 0; r < 4; ++r) acc[jt][r] = 0.f;

    if (t > 0) {  // h_{-1} == 0
      const unsigned short* hb = hs + ((size_t)arow * TSTEPS + (t - 1)) * HID + w * 256 + lk;
      Frag8 a[8];
      unsigned int valid = 0;  // wave-uniform bitmask of sentinel-free fragments
      do {
        // (re)issue loads ONLY for not-yet-valid fragments
        #pragma unroll
        for (int kc = 0; kc < 8; ++kc) {
          if (!(valid & (1u << kc))) {
            asm volatile("global_load_dwordx4 %0, %1, off offset:%2 sc0 sc1"
                         : "=v"(a[kc].d) : "v"(hb), "n"(kc * 64));
          }
        }
        asm volatile("s_waitcnt vmcnt(0)" ::: "memory");
        __builtin_amdgcn_sched_barrier(0);  // rule #18: checks must not hoist above the wait
        // validate each pending fragment; MFMA it the moment it is complete
        #pragma unroll
        for (int kc = 0; kc < 8; ++kc) {
          if (!(valid & (1u << kc))) {
            unsigned int mv = min(min(a[kc].d[0] ^ SENT, a[kc].d[1] ^ SENT),
                                  min(a[kc].d[2] ^ SENT, a[kc].d[3] ^ SENT));
            if (__all(mv != 0u)) {
              valid |= (1u << kc);
              #pragma unroll
              for (int jt = 0; jt < 4; ++jt)
                acc[jt] = __builtin_amdgcn_mfma_f32_16x16x32_bf16(a[kc].b, Bw[jt][kc].b, acc[jt], 0, 0, 0);
            }
          }
        }
      } while (valid != 0xFFu);
    }

    // cross-wave K-reduction via LDS
    #pragma unroll
    for (int jt = 0; jt < 4; ++jt)
      #pragma unroll
      for (int r = 0; r < 4; ++r)
        red[w][jt][(l >> 4) * 4 + r][l15] = acc[jt][r];
    __syncthreads();

    if (tid < 256) {
      float s0 = xv0, s1 = xv1;
      #pragma unroll
      for (int wv = 0; wv < 8; ++wv) {
        s0 += red[wv][jt_e][om][col];
        s1 += red[wv][jt_e][om][col + 1];
      }
      const float h0 = tanh_fast(s0), h1 = tanh_fast(s1);
      const unsigned int packed = (unsigned int)f2bf(h0) | ((unsigned int)f2bf(h1) << 16);
      // the signal: relaxed agent write-through store into the unique per-step slice
      unsigned int* hp = (unsigned int*)(hs + ((size_t)om * TSTEPS + t) * HID + jbase + oj2);
      __hip_atomic_store(hp, packed, __ATOMIC_RELAXED, __HIP_MEMORY_SCOPE_AGENT);
    }
    __syncthreads();  // red[] reuse discipline for next step
  }
}

extern "C" void kernel_launch(void* const* d_in, const int* in_sizes, int n_in,
                              void* d_out, int out_size, void* d_ws, size_t ws_size,
                              hipStream_t stream)
{
  (void)in_sizes; (void)n_in; (void)out_size; (void)ws_size;
  const float* x    = (const float*)d_in[0];
  const float* Wih  = (const float*)d_in[1];
  const float* bih  = (const float*)d_in[2];
  const float* Whh  = (const float*)d_in[3];
  const float* bhh  = (const float*)d_in[4];
  const float* Wout = (const float*)d_in[5];
  const float* bout = (const float*)d_in[6];
  float* out = (float*)d_out;

  char* ws = (char*)d_ws;
  float* xp          = (float*)(ws);                                // [512][8][2048] fp32, 32 MiB
  unsigned short* hs = (unsigned short*)(ws + (size_t)(32 << 20));  // [8][512][2048] bf16, 16 MiB

  // Phase 0: sentinel-fill hs
  sentinel_kernel<<<dim3(4096), 256, 0, stream>>>((u32x4*)hs);
  // Phase 1: xp = x @ W_ih^T + b_ih + b_hh
  gemm_kernel<0><<<dim3(64, 32), 256, 0, stream>>>(x, Wih, bih, bhh, xp, IN_K, HID);
  // Phase 2: barrier-free sequential scan (32 wgs, fan-in 4)
  scan_kernel<<<dim3(NWG), 512, 0, stream>>>(Whh, xp, hs);
  // Phase 3: out = hs @ W_out^T + b_out
  gemm_kernel<1><<<dim3(64, 2), 256, 0, stream>>>(hs, Wout, bout, nullptr, out, HID, OUTN);
}